// Round 9
// baseline (124.574 us; speedup 1.0000x reference)
//
#include <hip/hip_runtime.h>
#include <math.h>

#define NB 512
#define NS 64
#define ND 2048
#define NP 1024   // ND/2
#define NBLK 256  // <= capacity: 1024-thr blocks, worst-case 2/CU -> all resident

// ---------------- threefry2x32 (exact jax semantics, key=(0,42)) -------------
__device__ __forceinline__ unsigned rotl32(unsigned x, int d) {
    return (x << d) | (x >> (32 - d));
}

__device__ __forceinline__ void threefry2x32(unsigned k0, unsigned k1,
                                             unsigned& x0, unsigned& x1) {
    const unsigned ks0 = k0, ks1 = k1, ks2 = k0 ^ k1 ^ 0x1BD11BDAu;
    const int r0[4] = {13, 15, 26, 6};
    const int r1[4] = {17, 29, 16, 24};
    x0 += ks0; x1 += ks1;
#pragma unroll
    for (int i = 0; i < 4; ++i) { x0 += x1; x1 = rotl32(x1, r0[i]); x1 ^= x0; }
    x0 += ks1; x1 += ks2 + 1u;
#pragma unroll
    for (int i = 0; i < 4; ++i) { x0 += x1; x1 = rotl32(x1, r1[i]); x1 ^= x0; }
    x0 += ks2; x1 += ks0 + 2u;
#pragma unroll
    for (int i = 0; i < 4; ++i) { x0 += x1; x1 = rotl32(x1, r0[i]); x1 ^= x0; }
    x0 += ks0; x1 += ks1 + 3u;
#pragma unroll
    for (int i = 0; i < 4; ++i) { x0 += x1; x1 = rotl32(x1, r1[i]); x1 ^= x0; }
    x0 += ks1; x1 += ks2 + 4u;
#pragma unroll
    for (int i = 0; i < 4; ++i) { x0 += x1; x1 = rotl32(x1, r0[i]); x1 ^= x0; }
    x0 += ks2; x1 += ks0 + 5u;
}

// Fused: phase A = R8's k_MQ, grid barrier, phase B = R8's k_row.
// 256 blocks x 1024 threads (16 waves/CU). Barrier counter inits from the
// harness's uniform 0xAA poison via a never-written sentinel word (bar[0]);
// last-exiting block resets counters so non-repoisoned replays also work.
__global__ void __launch_bounds__(1024)
k_fused(const float* __restrict__ x, const float* __restrict__ amp,
        const float* __restrict__ ph, const float* __restrict__ G,
        const float* __restrict__ E, float* __restrict__ out,
        int* __restrict__ bar, float* __restrict__ M0, float* __restrict__ M1,
        float* __restrict__ Qt) {
    __shared__ __align__(16) char smem[16384];  // A: part4[4][256] / B: xs[2048]
    __shared__ float norm2[NS];
    __shared__ float W_l[NS], in_l[NS];
    __shared__ float Gl[NS * 4];
    __shared__ float partB[16][2][NS];
    __shared__ int o_sh[2];
    const int blk = blockIdx.x;
    const int tid = threadIdx.x;
    const int S = *(volatile int*)&bar[0];  // sentinel = uniform poison value
    const int srow = blk >> 2;

    // ---------------- phase A: norms+softmax (redundant) + M0/M1/Qt ----------
    {   // norms: 16 threads per amp row, float4, stride-16 interleave
        const int r = tid >> 4, sub = tid & 15;
        const float4* a4 = (const float4*)(amp + r * ND);  // 512 float4/row
        float acc = 0.f;
#pragma unroll 8
        for (int i = 0; i < 32; ++i) {
            float4 v = a4[sub + 16 * i];
            acc += v.x * v.x + v.y * v.y + v.z * v.z + v.w * v.w;
        }
        acc += __shfl_down(acc, 8, 16);
        acc += __shfl_down(acc, 4, 16);
        acc += __shfl_down(acc, 2, 16);
        acc += __shfl_down(acc, 1, 16);
        if (sub == 0) norm2[r] = acc;
    }
    if (tid < NS * 4) Gl[tid] = G[tid];
    __syncthreads();
    if (tid < NS) {  // wave 0: inv-norm + softmax of this block's E row
        in_l[tid] = 1.0f / sqrtf(norm2[tid]);
        float e = E[srow * NS + tid];
        float m = e;
        for (int off = 32; off; off >>= 1) m = fmaxf(m, __shfl_down(m, off));
        m = __shfl(m, 0);
        float ex = expf(e - m);
        float sum = ex;
        for (int off = 32; off; off >>= 1) sum += __shfl_down(sum, off);
        sum = __shfl(sum, 0);
        W_l[tid] = ex / sum;
    }
    __syncthreads();
    {   // main: thread = (pair pi, t-group of 16); partials to LDS
        float4* part4 = (float4*)smem;
        const int pi = tid & 255;
        const int tg = tid >> 8;  // 0..3
        const int p = ((blk & 3) << 8) + pi;
        const int t0 = tg << 4;
        const float2* a2 = (const float2*)amp;
        const float2* p2 = (const float2*)ph;
        float a0 = 0.f, a1 = 0.f, b0 = 0.f, b1 = 0.f;
#pragma unroll 4
        for (int t = t0; t < t0 + 16; ++t) {
            float2 av = a2[t * NP + p];
            float2 pv = p2[t * NP + p];
            float w = W_l[t], in = in_l[t];
            float ra0 = av.x * in * (__cosf(pv.x) + __sinf(pv.x));
            float ra1 = av.y * in * (__cosf(pv.y) + __sinf(pv.y));
            float wr0 = w * ra0, wr1 = w * ra1;
            a0 += wr0 * Gl[4 * t + 0];
            b0 += wr0 * Gl[4 * t + 2];
            a1 += wr1 * Gl[4 * t + 1];
            b1 += wr1 * Gl[4 * t + 3];
        }
        part4[tg * 256 + pi] = make_float4(a0, a1, b0, b1);
    }
    __syncthreads();
    if (tid < 256) {  // combine 4 partials, write M0/M1/Qt
        const float4* part4 = (const float4*)smem;
        const int p = ((blk & 3) << 8) + tid;
        float4 s0 = part4[0 * 256 + tid], s1 = part4[1 * 256 + tid],
               s2 = part4[2 * 256 + tid], s3 = part4[3 * 256 + tid];
        float a0 = s0.x + s1.x + s2.x + s3.x;
        float a1 = s0.y + s1.y + s2.y + s3.y;
        float b0 = s0.z + s1.z + s2.z + s3.z;
        float b1 = s0.w + s1.w + s2.w + s3.w;
        float2 m0v = {a0, a1}, m1v = {b0, b1};
        ((float2*)(M0 + srow * ND))[p] = m0v;
        ((float2*)(M1 + srow * ND))[p] = m1v;
        Qt[(3 * p + 0) * NS + srow] = a0 * a0 + a1 * a1;
        Qt[(3 * p + 1) * NS + srow] = a0 * b0 + a1 * b1;
        Qt[(3 * p + 2) * NS + srow] = b0 * b0 + b1 * b1;
    }

    // ---------------- grid barrier (release -> count -> poll -> acquire) -----
    __syncthreads();
    if (tid == 0) {
        __threadfence();                    // release: writeback this XCD's L2
        atomicAdd(&bar[1], 1);              // device-scope by default
        while (__hip_atomic_load(&bar[1], __ATOMIC_RELAXED,
                                 __HIP_MEMORY_SCOPE_AGENT) != S + NBLK)
            __builtin_amdgcn_s_sleep(16);   // ~1us backoff: no LLC hammering
        __threadfence();                    // acquire: drop stale L1/L2 lines
    }
    __syncthreads();

    // ---------------- phase B: logits + collapse + output (2 rows/block) -----
    {
        float2* xs = (float2*)smem;
        const int r0 = 2 * blk;
        ((float4*)xs)[tid] = ((const float4*)(x + r0 * ND))[tid];  // stage 2 rows
        __syncthreads();

        const int w = tid >> 6, s = tid & 63;
        {
            float acc0 = 0.f, acc1 = 0.f;
            const int p0 = w << 6;  // 64 pairs per wave
#pragma unroll 4
            for (int p = p0; p < p0 + 64; ++p) {
                float q0 = Qt[(3 * p + 0) * NS + s];
                float q1 = Qt[(3 * p + 1) * NS + s];
                float q2 = Qt[(3 * p + 2) * NS + s];
                float2 v0 = xs[p], v1 = xs[NP + p];
                acc0 += v0.x * v0.x * q0 + 2.f * v0.x * v0.y * q1 + v0.y * v0.y * q2;
                acc1 += v1.x * v1.x * q0 + 2.f * v1.x * v1.y * q1 + v1.y * v1.y * q2;
            }
            partB[w][0][s] = acc0;
            partB[w][1][s] = acc1;
        }
        __syncthreads();

        if (tid < 128) {  // waves 0-1: row r0+w2; exact jax categorical
            const int w2 = tid >> 6;
            float l = 0.f;
#pragma unroll
            for (int k = 0; k < 16; ++k) l += partB[k][w2][s];
            unsigned n = (unsigned)((r0 + w2) * NS + s);
            unsigned t0 = 0u, t1 = n;  // partitionable counter = (hi32, lo32)
            threefry2x32(0u, 42u, t0, t1);
            unsigned bits = t0 ^ t1;
            float u = (float)(bits >> 9) * (1.0f / 8388608.0f);
            u = fmaxf(u, 1.17549435e-38f);
            float g = -logf(-logf(u));
            float best = l + g;
            int bi = s;
            for (int off = 32; off; off >>= 1) {
                float ov = __shfl_down(best, off);
                int oi = __shfl_down(bi, off);
                if (ov > best || (ov == best && oi < bi)) { best = ov; bi = oi; }
            }
            if (s == 0) o_sh[w2] = bi;
        }
        __syncthreads();

#pragma unroll
        for (int r = 0; r < 2; ++r) {
            const int o = o_sh[r];
            const float2* m0p = (const float2*)(M0 + o * ND);
            const float2* m1p = (const float2*)(M1 + o * ND);
            const float2* xr = xs + r * NP;
            float2* op = (float2*)(out + (r0 + r) * ND);
            float2 xv = xr[tid], m0 = m0p[tid], m1 = m1p[tid];
            float2 rr;
            rr.x = xv.x * m0.x + xv.y * m1.x;
            rr.y = xv.x * m0.y + xv.y * m1.y;
            op[tid] = rr;
        }
    }

    // exit cleanup: last block restores counters to sentinel (for replays
    // without re-poison; harness re-poisons anyway).
    if (tid == 0) {
        __threadfence();
        int old = atomicAdd(&bar[2], 1);
        if (old == S + NBLK - 1) {
            atomicExch(&bar[1], S);
            atomicExch(&bar[2], S);
        }
    }
}

extern "C" void kernel_launch(void* const* d_in, const int* in_sizes, int n_in,
                              void* d_out, int out_size, void* d_ws, size_t ws_size,
                              hipStream_t stream) {
    const float* x   = (const float*)d_in[0];  // [512,2048]
    const float* amp = (const float*)d_in[1];  // [64,2048]
    const float* ph  = (const float*)d_in[2];  // [64,2048]
    const float* G   = (const float*)d_in[3];  // [64,2,2]
    const float* E   = (const float*)d_in[4];  // [64,64]
    float* out = (float*)d_out;
    float* ws = (float*)d_ws;

    // ws layout (float offsets). bar[0] = sentinel (never written).
    int*   bar = (int*)ws;       // 16 ints
    float* M0  = ws + 16;        // 131072
    float* M1  = ws + 131088;    // 131072
    float* Qt  = ws + 262160;    // 196608 (ends ~1.83 MB)

    k_fused<<<NBLK, 1024, 0, stream>>>(x, amp, ph, G, E, out, bar, M0, M1, Qt);
}

// Round 10
// 99.490 us; speedup vs baseline: 1.2521x; 1.2521x over previous
//
#include <hip/hip_runtime.h>
#include <math.h>

#define NB 512
#define NS 64
#define ND 2048
#define NP 1024   // ND/2

// ---------------- threefry2x32 (exact jax semantics, key=(0,42)) -------------
__device__ __forceinline__ unsigned rotl32(unsigned x, int d) {
    return (x << d) | (x >> (32 - d));
}

__device__ __forceinline__ void threefry2x32(unsigned k0, unsigned k1,
                                             unsigned& x0, unsigned& x1) {
    const unsigned ks0 = k0, ks1 = k1, ks2 = k0 ^ k1 ^ 0x1BD11BDAu;
    const int r0[4] = {13, 15, 26, 6};
    const int r1[4] = {17, 29, 16, 24};
    x0 += ks0; x1 += ks1;
#pragma unroll
    for (int i = 0; i < 4; ++i) { x0 += x1; x1 = rotl32(x1, r0[i]); x1 ^= x0; }
    x0 += ks1; x1 += ks2 + 1u;
#pragma unroll
    for (int i = 0; i < 4; ++i) { x0 += x1; x1 = rotl32(x1, r1[i]); x1 ^= x0; }
    x0 += ks2; x1 += ks0 + 2u;
#pragma unroll
    for (int i = 0; i < 4; ++i) { x0 += x1; x1 = rotl32(x1, r0[i]); x1 ^= x0; }
    x0 += ks0; x1 += ks1 + 3u;
#pragma unroll
    for (int i = 0; i < 4; ++i) { x0 += x1; x1 = rotl32(x1, r1[i]); x1 ^= x0; }
    x0 += ks1; x1 += ks2 + 4u;
#pragma unroll
    for (int i = 0; i < 4; ++i) { x0 += x1; x1 = rotl32(x1, r0[i]); x1 ^= x0; }
    x0 += ks2; x1 += ks0 + 5u;
}

// ---------------- K1: norms+softmax (redundant per block) + M0/M1/Qt ---------
// 256 blocks x 1024 threads: s-row = blk>>2, pair chunk = (blk&3)*256.
// t-loop split 4x across wave-groups (16 t each) -> 4 waves/SIMD. (R8-verified)
__global__ void __launch_bounds__(1024)
k_MQ(const float* __restrict__ amp, const float* __restrict__ ph,
     const float* __restrict__ G, const float* __restrict__ E,
     float* __restrict__ M0, float* __restrict__ M1, float* __restrict__ Qt) {
    __shared__ float norm2[NS];
    __shared__ float W_l[NS], in_l[NS];
    __shared__ float Gl[NS * 4];
    __shared__ float4 part4[4][256];   // 16 KB: per-tgroup partial (a0,a1,b0,b1)
    const int blk = blockIdx.x;
    const int tid = threadIdx.x;
    const int srow = blk >> 2;

    // redundant norms: 16 threads per amp row, float4 loads, stride-16 interleave
    {
        const int r = tid >> 4, sub = tid & 15;
        const float4* a4 = (const float4*)(amp + r * ND);  // 512 float4/row
        float acc = 0.f;
#pragma unroll 8
        for (int i = 0; i < 32; ++i) {
            float4 v = a4[sub + 16 * i];
            acc += v.x * v.x + v.y * v.y + v.z * v.z + v.w * v.w;
        }
        acc += __shfl_down(acc, 8, 16);
        acc += __shfl_down(acc, 4, 16);
        acc += __shfl_down(acc, 2, 16);
        acc += __shfl_down(acc, 1, 16);
        if (sub == 0) norm2[r] = acc;
    }
    if (tid < NS * 4) Gl[tid] = G[tid];
    __syncthreads();
    if (tid < NS) {  // wave 0: inv-norm + softmax of this block's E row
        in_l[tid] = 1.0f / sqrtf(norm2[tid]);
        float e = E[srow * NS + tid];
        float m = e;
        for (int off = 32; off; off >>= 1) m = fmaxf(m, __shfl_down(m, off));
        m = __shfl(m, 0);
        float ex = expf(e - m);
        float sum = ex;
        for (int off = 32; off; off >>= 1) sum += __shfl_down(sum, off);
        sum = __shfl(sum, 0);
        W_l[tid] = ex / sum;
    }
    __syncthreads();

    // main: thread = (pair pi, t-group); 16 t's each, partials to LDS
    {
        const int pi = tid & 255;
        const int tg = tid >> 8;           // 0..3
        const int p = ((blk & 3) << 8) + pi;
        const int t0 = tg << 4;
        const float2* a2 = (const float2*)amp;
        const float2* p2 = (const float2*)ph;
        float a0 = 0.f, a1 = 0.f, b0 = 0.f, b1 = 0.f;
#pragma unroll 4
        for (int t = t0; t < t0 + 16; ++t) {
            float2 av = a2[t * NP + p];
            float2 pv = p2[t * NP + p];
            float w = W_l[t], in = in_l[t];
            float ra0 = av.x * in * (__cosf(pv.x) + __sinf(pv.x));
            float ra1 = av.y * in * (__cosf(pv.y) + __sinf(pv.y));
            float wr0 = w * ra0, wr1 = w * ra1;
            a0 += wr0 * Gl[4 * t + 0];
            b0 += wr0 * Gl[4 * t + 2];
            a1 += wr1 * Gl[4 * t + 1];
            b1 += wr1 * Gl[4 * t + 3];
        }
        part4[tg][pi] = make_float4(a0, a1, b0, b1);
    }
    __syncthreads();

    if (tid < 256) {  // combine 4 partials, write M0/M1/Qt
        const int p = ((blk & 3) << 8) + tid;
        float4 s0 = part4[0][tid], s1 = part4[1][tid],
               s2 = part4[2][tid], s3 = part4[3][tid];
        float a0 = s0.x + s1.x + s2.x + s3.x;
        float a1 = s0.y + s1.y + s2.y + s3.y;
        float b0 = s0.z + s1.z + s2.z + s3.z;
        float b1 = s0.w + s1.w + s2.w + s3.w;
        float2 m0v = {a0, a1}, m1v = {b0, b1};
        ((float2*)(M0 + srow * ND))[p] = m0v;
        ((float2*)(M1 + srow * ND))[p] = m1v;
        Qt[(3 * p + 0) * NS + srow] = a0 * a0 + a1 * a1;
        Qt[(3 * p + 1) * NS + srow] = a0 * b0 + a1 * b1;
        Qt[(3 * p + 2) * NS + srow] = b0 * b0 + b1 * b1;
    }
}

// ---------------- K2: logits + collapse + output; 4 rows/block ---------------
// 128 blocks x 1024 threads (16 waves): wave w = p-chunk [64w,64w+64), all 4
// rows. Halves per-XCD Qt L2 traffic vs 2 rows/block; logits bit-identical to
// R8 (same per-wave p-chunk, same k=0..15 combine order per row).
__global__ void __launch_bounds__(1024)
k_row(const float* __restrict__ x, const float* __restrict__ Qt,
      const float* __restrict__ M0, const float* __restrict__ M1,
      float* __restrict__ out) {
    __shared__ float2 xs[4 * NP];      // 32 KB: four x rows, as pairs
    __shared__ float part[16][4][NS];  // 16 KB
    __shared__ int o_sh[4];
    const int blk = blockIdx.x;
    const int tid = threadIdx.x;
    const int r0 = 4 * blk;

    // stage 4 x rows (coalesced float4: 2048 of them)
    ((float4*)xs)[tid] = ((const float4*)(x + r0 * ND))[tid];
    ((float4*)xs)[tid + 1024] = ((const float4*)(x + r0 * ND))[tid + 1024];
    __syncthreads();

    const int w = tid >> 6, s = tid & 63;
    {
        float acc0 = 0.f, acc1 = 0.f, acc2 = 0.f, acc3 = 0.f;
        const int p0 = w << 6;  // 64 pairs per wave
#pragma unroll 4
        for (int p = p0; p < p0 + 64; ++p) {
            float q0 = Qt[(3 * p + 0) * NS + s];
            float q1 = Qt[(3 * p + 1) * NS + s];
            float q2 = Qt[(3 * p + 2) * NS + s];
            float2 v0 = xs[p], v1 = xs[NP + p], v2 = xs[2 * NP + p], v3 = xs[3 * NP + p];
            acc0 += v0.x * v0.x * q0 + 2.f * v0.x * v0.y * q1 + v0.y * v0.y * q2;
            acc1 += v1.x * v1.x * q0 + 2.f * v1.x * v1.y * q1 + v1.y * v1.y * q2;
            acc2 += v2.x * v2.x * q0 + 2.f * v2.x * v2.y * q1 + v2.y * v2.y * q2;
            acc3 += v3.x * v3.x * q0 + 2.f * v3.x * v3.y * q1 + v3.y * v3.y * q2;
        }
        part[w][0][s] = acc0;
        part[w][1][s] = acc1;
        part[w][2][s] = acc2;
        part[w][3][s] = acc3;
    }
    __syncthreads();

    if (tid < 256) {  // waves 0-3: row r0+w2; exact jax categorical (gumbel-max)
        const int w2 = tid >> 6;
        float l = 0.f;
#pragma unroll
        for (int k = 0; k < 16; ++k) l += part[k][w2][s];
        unsigned n = (unsigned)((r0 + w2) * NS + s);
        unsigned t0 = 0u, t1 = n;  // partitionable counter = (hi32(n), lo32(n))
        threefry2x32(0u, 42u, t0, t1);
        unsigned bits = t0 ^ t1;
        float u = (float)(bits >> 9) * (1.0f / 8388608.0f);
        u = fmaxf(u, 1.17549435e-38f);
        float g = -logf(-logf(u));
        float best = l + g;
        int bi = s;
        for (int off = 32; off; off >>= 1) {
            float ov = __shfl_down(best, off);
            int oi = __shfl_down(bi, off);
            if (ov > best || (ov == best && oi < bi)) { best = ov; bi = oi; }
        }
        if (s == 0) o_sh[w2] = bi;
    }
    __syncthreads();

#pragma unroll
    for (int r = 0; r < 4; ++r) {
        const int o = o_sh[r];
        const float2* m0p = (const float2*)(M0 + o * ND);
        const float2* m1p = (const float2*)(M1 + o * ND);
        const float2* xr = xs + r * NP;
        float2* op = (float2*)(out + (r0 + r) * ND);
        float2 xv = xr[tid], m0 = m0p[tid], m1 = m1p[tid];
        float2 rr;
        rr.x = xv.x * m0.x + xv.y * m1.x;
        rr.y = xv.x * m0.y + xv.y * m1.y;
        op[tid] = rr;
    }
}

extern "C" void kernel_launch(void* const* d_in, const int* in_sizes, int n_in,
                              void* d_out, int out_size, void* d_ws, size_t ws_size,
                              hipStream_t stream) {
    const float* x   = (const float*)d_in[0];  // [512,2048]
    const float* amp = (const float*)d_in[1];  // [64,2048]
    const float* ph  = (const float*)d_in[2];  // [64,2048]
    const float* G   = (const float*)d_in[3];  // [64,2,2]
    const float* E   = (const float*)d_in[4];  // [64,64]
    float* out = (float*)d_out;
    float* ws = (float*)d_ws;

    // ws layout (float offsets)
    float* M0 = ws;             // 131072
    float* M1 = ws + 131072;    // 131072
    float* Qt = ws + 262144;    // 196608 (ends ~1.83 MB)

    k_MQ <<<256, 1024, 0, stream>>>(amp, ph, G, E, M0, M1, Qt);
    k_row<<<128, 1024, 0, stream>>>(x, Qt, M0, M1, out);
}

// Round 11
// 89.451 us; speedup vs baseline: 1.3927x; 1.1122x over previous
//
#include <hip/hip_runtime.h>
#include <math.h>

#define NB 512
#define NS 64
#define ND 2048
#define NP 1024   // ND/2

// ---------------- threefry2x32 (exact jax semantics, key=(0,42)) -------------
__device__ __forceinline__ unsigned rotl32(unsigned x, int d) {
    return (x << d) | (x >> (32 - d));
}

__device__ __forceinline__ void threefry2x32(unsigned k0, unsigned k1,
                                             unsigned& x0, unsigned& x1) {
    const unsigned ks0 = k0, ks1 = k1, ks2 = k0 ^ k1 ^ 0x1BD11BDAu;
    const int r0[4] = {13, 15, 26, 6};
    const int r1[4] = {17, 29, 16, 24};
    x0 += ks0; x1 += ks1;
#pragma unroll
    for (int i = 0; i < 4; ++i) { x0 += x1; x1 = rotl32(x1, r0[i]); x1 ^= x0; }
    x0 += ks1; x1 += ks2 + 1u;
#pragma unroll
    for (int i = 0; i < 4; ++i) { x0 += x1; x1 = rotl32(x1, r1[i]); x1 ^= x0; }
    x0 += ks2; x1 += ks0 + 2u;
#pragma unroll
    for (int i = 0; i < 4; ++i) { x0 += x1; x1 = rotl32(x1, r0[i]); x1 ^= x0; }
    x0 += ks0; x1 += ks1 + 3u;
#pragma unroll
    for (int i = 0; i < 4; ++i) { x0 += x1; x1 = rotl32(x1, r1[i]); x1 ^= x0; }
    x0 += ks1; x1 += ks2 + 4u;
#pragma unroll
    for (int i = 0; i < 4; ++i) { x0 += x1; x1 = rotl32(x1, r0[i]); x1 ^= x0; }
    x0 += ks2; x1 += ks0 + 5u;
}

// ---------------- K1: norms+softmax (redundant per block) + M0/M1/Qt ---------
// 256 blocks x 1024 threads: s-row = blk>>2, pair chunk = (blk&3)*256.
// t-loop split 4x across wave-groups (16 t each) -> 4 waves/SIMD. (R8-verified)
// Qt layout: [p][s][3] -> 12 contiguous bytes per (p,s) triple.
__global__ void __launch_bounds__(1024)
k_MQ(const float* __restrict__ amp, const float* __restrict__ ph,
     const float* __restrict__ G, const float* __restrict__ E,
     float* __restrict__ M0, float* __restrict__ M1, float* __restrict__ Qt) {
    __shared__ float norm2[NS];
    __shared__ float W_l[NS], in_l[NS];
    __shared__ float Gl[NS * 4];
    __shared__ float4 part4[4][256];   // 16 KB: per-tgroup partial (a0,a1,b0,b1)
    const int blk = blockIdx.x;
    const int tid = threadIdx.x;
    const int srow = blk >> 2;

    // redundant norms: 16 threads per amp row, float4 loads, stride-16 interleave
    {
        const int r = tid >> 4, sub = tid & 15;
        const float4* a4 = (const float4*)(amp + r * ND);  // 512 float4/row
        float acc = 0.f;
#pragma unroll 8
        for (int i = 0; i < 32; ++i) {
            float4 v = a4[sub + 16 * i];
            acc += v.x * v.x + v.y * v.y + v.z * v.z + v.w * v.w;
        }
        acc += __shfl_down(acc, 8, 16);
        acc += __shfl_down(acc, 4, 16);
        acc += __shfl_down(acc, 2, 16);
        acc += __shfl_down(acc, 1, 16);
        if (sub == 0) norm2[r] = acc;
    }
    if (tid < NS * 4) Gl[tid] = G[tid];
    __syncthreads();
    if (tid < NS) {  // wave 0: inv-norm + softmax of this block's E row
        in_l[tid] = 1.0f / sqrtf(norm2[tid]);
        float e = E[srow * NS + tid];
        float m = e;
        for (int off = 32; off; off >>= 1) m = fmaxf(m, __shfl_down(m, off));
        m = __shfl(m, 0);
        float ex = expf(e - m);
        float sum = ex;
        for (int off = 32; off; off >>= 1) sum += __shfl_down(sum, off);
        sum = __shfl(sum, 0);
        W_l[tid] = ex / sum;
    }
    __syncthreads();

    // main: thread = (pair pi, t-group); 16 t's each, partials to LDS
    {
        const int pi = tid & 255;
        const int tg = tid >> 8;           // 0..3
        const int p = ((blk & 3) << 8) + pi;
        const int t0 = tg << 4;
        const float2* a2 = (const float2*)amp;
        const float2* p2 = (const float2*)ph;
        float a0 = 0.f, a1 = 0.f, b0 = 0.f, b1 = 0.f;
#pragma unroll 4
        for (int t = t0; t < t0 + 16; ++t) {
            float2 av = a2[t * NP + p];
            float2 pv = p2[t * NP + p];
            float w = W_l[t], in = in_l[t];
            float ra0 = av.x * in * (__cosf(pv.x) + __sinf(pv.x));
            float ra1 = av.y * in * (__cosf(pv.y) + __sinf(pv.y));
            float wr0 = w * ra0, wr1 = w * ra1;
            a0 += wr0 * Gl[4 * t + 0];
            b0 += wr0 * Gl[4 * t + 2];
            a1 += wr1 * Gl[4 * t + 1];
            b1 += wr1 * Gl[4 * t + 3];
        }
        part4[tg][pi] = make_float4(a0, a1, b0, b1);
    }
    __syncthreads();

    if (tid < 256) {  // combine 4 partials, write M0/M1/Qt
        const int p = ((blk & 3) << 8) + tid;
        float4 s0 = part4[0][tid], s1 = part4[1][tid],
               s2 = part4[2][tid], s3 = part4[3][tid];
        float a0 = s0.x + s1.x + s2.x + s3.x;
        float a1 = s0.y + s1.y + s2.y + s3.y;
        float b0 = s0.z + s1.z + s2.z + s3.z;
        float b1 = s0.w + s1.w + s2.w + s3.w;
        float2 m0v = {a0, a1}, m1v = {b0, b1};
        ((float2*)(M0 + srow * ND))[p] = m0v;
        ((float2*)(M1 + srow * ND))[p] = m1v;
        float* qp = Qt + p * 192 + srow * 3;   // [p][s][3], 12 B contiguous
        qp[0] = a0 * a0 + a1 * a1;
        qp[1] = a0 * b0 + a1 * b1;
        qp[2] = b0 * b0 + b1 * b1;
    }
}

// ---------------- K2: logits + collapse + output; 2 rows/block ---------------
// 256 blocks x 1024 threads (16 waves, 4/SIMD): wave w = p-chunk [64w,64w+64),
// both rows. Qt triple = one dwordx3 load per (p,s). (R8-verified structure)
__global__ void __launch_bounds__(1024)
k_row(const float* __restrict__ x, const float* __restrict__ Qt,
      const float* __restrict__ M0, const float* __restrict__ M1,
      float* __restrict__ out) {
    __shared__ float2 xs[2 * NP];      // 16 KB: two x rows, as pairs
    __shared__ float part[16][2][NS];  // 8 KB
    __shared__ int o_sh[2];
    const int blk = blockIdx.x;
    const int tid = threadIdx.x;
    const int r0 = 2 * blk;

    // stage 2 x rows (coalesced float4: 1024 of them)
    ((float4*)xs)[tid] = ((const float4*)(x + r0 * ND))[tid];
    __syncthreads();

    const int w = tid >> 6, s = tid & 63;
    {
        float acc0 = 0.f, acc1 = 0.f;
        const int p0 = w << 6;  // 64 pairs per wave
#pragma unroll 4
        for (int p = p0; p < p0 + 64; ++p) {
            const float* qp = Qt + p * 192 + s * 3;  // 12 B contiguous triple
            float q0 = qp[0];
            float q1 = qp[1];
            float q2 = qp[2];
            float2 v0 = xs[p], v1 = xs[NP + p];
            acc0 += v0.x * v0.x * q0 + 2.f * v0.x * v0.y * q1 + v0.y * v0.y * q2;
            acc1 += v1.x * v1.x * q0 + 2.f * v1.x * v1.y * q1 + v1.y * v1.y * q2;
        }
        part[w][0][s] = acc0;
        part[w][1][s] = acc1;
    }
    __syncthreads();

    if (tid < 128) {  // waves 0-1: row r0+w2; exact jax categorical (gumbel-max)
        const int w2 = tid >> 6;
        float l = 0.f;
#pragma unroll
        for (int k = 0; k < 16; ++k) l += part[k][w2][s];
        unsigned n = (unsigned)((r0 + w2) * NS + s);
        unsigned t0 = 0u, t1 = n;  // partitionable counter = (hi32(n), lo32(n))
        threefry2x32(0u, 42u, t0, t1);
        unsigned bits = t0 ^ t1;
        float u = (float)(bits >> 9) * (1.0f / 8388608.0f);
        u = fmaxf(u, 1.17549435e-38f);
        float g = -logf(-logf(u));
        float best = l + g;
        int bi = s;
        for (int off = 32; off; off >>= 1) {
            float ov = __shfl_down(best, off);
            int oi = __shfl_down(bi, off);
            if (ov > best || (ov == best && oi < bi)) { best = ov; bi = oi; }
        }
        if (s == 0) o_sh[w2] = bi;
    }
    __syncthreads();

#pragma unroll
    for (int r = 0; r < 2; ++r) {
        const int o = o_sh[r];
        const float2* m0p = (const float2*)(M0 + o * ND);
        const float2* m1p = (const float2*)(M1 + o * ND);
        const float2* xr = xs + r * NP;
        float2* op = (float2*)(out + (r0 + r) * ND);
        float2 xv = xr[tid], m0 = m0p[tid], m1 = m1p[tid];
        float2 rr;
        rr.x = xv.x * m0.x + xv.y * m1.x;
        rr.y = xv.x * m0.y + xv.y * m1.y;
        op[tid] = rr;
    }
}

extern "C" void kernel_launch(void* const* d_in, const int* in_sizes, int n_in,
                              void* d_out, int out_size, void* d_ws, size_t ws_size,
                              hipStream_t stream) {
    const float* x   = (const float*)d_in[0];  // [512,2048]
    const float* amp = (const float*)d_in[1];  // [64,2048]
    const float* ph  = (const float*)d_in[2];  // [64,2048]
    const float* G   = (const float*)d_in[3];  // [64,2,2]
    const float* E   = (const float*)d_in[4];  // [64,64]
    float* out = (float*)d_out;
    float* ws = (float*)d_ws;

    // ws layout (float offsets)
    float* M0 = ws;             // 131072
    float* M1 = ws + 131072;    // 131072
    float* Qt = ws + 262144;    // 196608 (ends ~1.83 MB)

    k_MQ <<<256, 1024, 0, stream>>>(amp, ph, G, E, M0, M1, Qt);
    k_row<<<256, 1024, 0, stream>>>(x, Qt, M0, M1, out);
}